// Round 16
// baseline (179.259 us; speedup 1.0000x reference)
//
#include <hip/hip_runtime.h>
#include <hip/hip_fp16.h>

#define N_NODES 50000
#define N_EDGES 800000
#define NREL 32
#define NEG_SLOPE 0.2f
#define SCAN_NB ((N_NODES + 255) / 256)   // 196
#define HIST_NB ((N_EDGES + 255) / 256)   // 3125
#define NXB 256                           // nx blocks in MEGA
#define NTILES (N_NODES / 16)             // 3125 wave tiles (exact)

typedef _Float16 f16x8 __attribute__((ext_vector_type(8)));
typedef float f32x4 __attribute__((ext_vector_type(4)));

// ---------------- MEGA: nx_mfma (blocks 0..255) ∥ hist (256..3380) ∥ rel (3381..3412) ----------------
__global__ __launch_bounds__(256) void mega_kernel(
    const float* __restrict__ x, const float* __restrict__ W,
    const float* __restrict__ att_src, const float* __restrict__ att_dst,
    __half* __restrict__ xh, float* __restrict__ a_src, float* __restrict__ a_dst,
    const int* __restrict__ ei, int* __restrict__ counts, int* __restrict__ rank,
    const float* __restrict__ rel_emb, const float* __restrict__ W_e,
    const float* __restrict__ att_edge, float* __restrict__ a_edge_r)
{
    __shared__ __align__(16) _Float16 Wl[272][72];
    int tid = threadIdx.x;
    int bid = blockIdx.x;

    if (bid >= NXB) {
        if (bid < NXB + HIST_NB) {
            // ---- histogram + rank ----
            int e = (bid - NXB) * 256 + tid;
            if (e < N_EDGES) {
                int r = atomicAdd(&counts[ei[N_EDGES + e]], 1);
                __builtin_nontemporal_store(r, &rank[e]);
            }
        } else if (tid < 64) {
            // ---- relation table row r ----
            int r = bid - (NXB + HIST_NB);
            int h = tid >> 4;
            int i16 = tid & 15;
            float rr = rel_emb[r * 64 + tid];
            float4 acc = {0.f, 0.f, 0.f, 0.f};
            #pragma unroll
            for (int k = 0; k < 64; ++k) {
                float rv = __shfl(rr, k);
                float4 wv = *(const float4*)(W_e + k * 256 + h * 64 + i16 * 4);
                acc.x += rv * wv.x; acc.y += rv * wv.y;
                acc.z += rv * wv.z; acc.w += rv * wv.w;
            }
            float4 aev = *(const float4*)(att_edge + h * 64 + i16 * 4);
            float ae = acc.x * aev.x + acc.y * aev.y + acc.z * aev.z + acc.w * aev.w;
            #pragma unroll
            for (int m = 8; m >= 1; m >>= 1) ae += __shfl_xor(ae, m);
            if (i16 == 0) a_edge_r[r * 4 + h] = ae;
        }
        return;
    }

    // ---- node transform via MFMA ----
    for (int idx = tid; idx < 64 * 256; idx += 256) {
        int k = idx >> 8, col = idx & 255;
        Wl[col][k] = (_Float16)W[idx];
    }
    // vsd computed inline (fp32 accumulate): cols 256..263; zero 264..271
    for (int idx = tid; idx < 512; idx += 256) {
        int k = idx & 63;
        int col8 = idx >> 6;
        int h = col8 >> 1;
        const float* att = (col8 & 1) ? att_dst : att_src;
        float s = 0.f;
        #pragma unroll 8
        for (int c = 0; c < 64; ++c)
            s += W[k * 256 + h * 64 + c] * att[h * 64 + c];
        Wl[256 + col8][k] = (_Float16)s;
        Wl[264 + col8][k] = (_Float16)0.f;
    }
    __syncthreads();

    int lane = tid & 63;
    int wv = tid >> 6;
    int r16 = lane & 15;
    int kg = lane >> 4;

    for (int tile = bid * 4 + wv; tile < NTILES; tile += NXB * 4) {
        int nb = tile * 16;
        const float* __restrict__ xrow = x + (size_t)(nb + r16) * 64 + kg * 8;
        float4 u0 = *(const float4*)(xrow);
        float4 u1 = *(const float4*)(xrow + 4);
        float4 u2 = *(const float4*)(xrow + 32);
        float4 u3 = *(const float4*)(xrow + 36);
        f16x8 A0, A1;
        A0[0] = (_Float16)u0.x; A0[1] = (_Float16)u0.y;
        A0[2] = (_Float16)u0.z; A0[3] = (_Float16)u0.w;
        A0[4] = (_Float16)u1.x; A0[5] = (_Float16)u1.y;
        A0[6] = (_Float16)u1.z; A0[7] = (_Float16)u1.w;
        A1[0] = (_Float16)u2.x; A1[1] = (_Float16)u2.y;
        A1[2] = (_Float16)u2.z; A1[3] = (_Float16)u2.w;
        A1[4] = (_Float16)u3.x; A1[5] = (_Float16)u3.y;
        A1[6] = (_Float16)u3.z; A1[7] = (_Float16)u3.w;

        f32x4 D[17];
        #pragma unroll
        for (int ct = 0; ct < 17; ++ct) {
            f16x8 B0 = *(const f16x8*)&Wl[ct * 16 + r16][kg * 8];
            f16x8 B1 = *(const f16x8*)&Wl[ct * 16 + r16][32 + kg * 8];
            f32x4 d = {0.f, 0.f, 0.f, 0.f};
            d = __builtin_amdgcn_mfma_f32_16x16x32_f16(A0, B0, d, 0, 0, 0);
            d = __builtin_amdgcn_mfma_f32_16x16x32_f16(A1, B1, d, 0, 0, 0);
            D[ct] = d;
        }

        #pragma unroll
        for (int r = 0; r < 4; ++r) {
            int n = nb + kg * 4 + r;
            #pragma unroll
            for (int j = 0; j < 4; ++j) {
                __half2 lo = __floats2half2_rn(D[j][r], D[j + 4][r]);
                __half2 hi = __floats2half2_rn(D[j + 8][r], D[j + 12][r]);
                uint2 pk;
                pk.x = *(unsigned int*)&lo;
                pk.y = *(unsigned int*)&hi;
                *(uint2*)(xh + (size_t)n * 256 + (j * 16 + r16) * 4) = pk;
            }
            if (r16 < 8) {
                float v = D[16][r];
                int h = r16 >> 1;
                if (r16 & 1) a_dst[n * 4 + h] = v;
                else         a_src[n * 4 + h] = v;
            }
        }
    }
}

// ---------------- fused scan: block b derives its own base, scans its segment ----------------
__global__ __launch_bounds__(256) void scan_fused(const int* __restrict__ counts,
                                                  int* __restrict__ offsets) {
    __shared__ int sh[256];
    __shared__ int wsums[4];
    int tid = threadIdx.x;
    int b = blockIdx.x;
    int lane = tid & 63;
    int warp = tid >> 6;

    // base = sum of counts[0 .. b*256)  (coalesced strided reads, L2-hit)
    int limit = b * 256;
    int acc = 0;
    for (int i = tid; i < limit; i += 256) acc += counts[i];
    #pragma unroll
    for (int m = 32; m >= 1; m >>= 1) acc += __shfl_xor(acc, m);
    if (lane == 0) wsums[warp] = acc;
    __syncthreads();
    int base = wsums[0] + wsums[1] + wsums[2] + wsums[3];

    // local exclusive scan of this block's segment
    int i = b * 256 + tid;
    int v = (i < N_NODES) ? counts[i] : 0;
    sh[tid] = v;
    __syncthreads();
    #pragma unroll
    for (int off = 1; off < 256; off <<= 1) {
        int t = (tid >= off) ? sh[tid - off] : 0;
        __syncthreads();
        sh[tid] += t;
        __syncthreads();
    }
    if (i < N_NODES) offsets[i] = base + sh[tid] - v;
}

// ---------------- scatter: pos = offsets[d] + rank[e]  (no atomic, nt streams) ----------------
__global__ __launch_bounds__(256) void scatter_kernel(const int* __restrict__ ei,
                                                      const int* __restrict__ etype,
                                                      const int* __restrict__ offsets,
                                                      const int* __restrict__ rank,
                                                      int* __restrict__ elist) {
    int e = blockIdx.x * 256 + threadIdx.x;
    if (e >= N_EDGES) return;
    int s = __builtin_nontemporal_load(&ei[e]);
    int d = __builtin_nontemporal_load(&ei[N_EDGES + e]);
    int t = __builtin_nontemporal_load(&etype[e]);
    int rk = __builtin_nontemporal_load(&rank[e]);
    int pos = offsets[d] + rk;
    elist[pos] = (s << 5) | t;
}

// ---------------- aggregate (2 waves per dst node, inline exp) ----------------
__global__ __launch_bounds__(256) void aggregate(
    const int* __restrict__ offsets, const int* __restrict__ counts,
    const int* __restrict__ elist, const float* __restrict__ a_src,
    const float* __restrict__ a_dst, const float* __restrict__ a_edge_r,
    const __half* __restrict__ xh, const float* __restrict__ bias,
    float* __restrict__ out)
{
    __shared__ float4 exsh[4][64];
    __shared__ int    ssh[4][64];
    __shared__ float4 pnum[4][64];
    __shared__ float4 pden[4][64];

    int lane = threadIdx.x & 63;
    int warp = threadIdx.x >> 6;   // 0..3
    int pair = warp >> 1;
    int half = warp & 1;
    int d = blockIdx.x * 2 + pair;

    int beg = offsets[d];
    int deg = counts[d];
    int h1 = (deg + 1) >> 1;
    int mybeg = beg + (half ? h1 : 0);
    int mydeg = half ? (deg - h1) : h1;

    float4 advec = ((const float4*)a_dst)[d];

    float n0 = 0.f, n1 = 0.f, n2 = 0.f, n3 = 0.f;
    float d0 = 0.f, d1 = 0.f, d2 = 0.f, d3 = 0.f;

    for (int base = 0; base < mydeg; base += 64) {
        int m = mydeg - base; if (m > 64) m = 64;

        float4 ev = make_float4(0.f, 0.f, 0.f, 0.f);
        int s = 0;
        if (lane < m) {
            int pk = __builtin_nontemporal_load(&elist[mybeg + base + lane]);
            s = pk >> 5;
            int t = pk & 31;
            float4 as = ((const float4*)a_src)[s];
            float4 ae = ((const float4*)a_edge_r)[t];
            float b0 = as.x + advec.x + ae.x; b0 = b0 > 0.f ? b0 : NEG_SLOPE * b0;
            float b1 = as.y + advec.y + ae.y; b1 = b1 > 0.f ? b1 : NEG_SLOPE * b1;
            float b2 = as.z + advec.z + ae.z; b2 = b2 > 0.f ? b2 : NEG_SLOPE * b2;
            float b3 = as.w + advec.w + ae.w; b3 = b3 > 0.f ? b3 : NEG_SLOPE * b3;
            ev.x = __expf(b0); ev.y = __expf(b1);
            ev.z = __expf(b2); ev.w = __expf(b3);
        }
        d0 += ev.x; d1 += ev.y; d2 += ev.z; d3 += ev.w;
        exsh[warp][lane] = ev;   // wave-private rows; wave-synchronous RAW
        ssh[warp][lane]  = s;

        #pragma unroll 4
        for (int j = 0; j < m; ++j) {
            float4 e = exsh[warp][j];   // broadcast read (no conflict)
            int sj = ssh[warp][j];
            const __half2* __restrict__ xr =
                (const __half2*)(xh + (size_t)sj * 256 + lane * 4);
            __half2 p0 = xr[0], p1 = xr[1];
            float2 f0 = __half22float2(p0), f1 = __half22float2(p1);
            n0 = fmaf(e.x, f0.x, n0);
            n1 = fmaf(e.y, f0.y, n1);
            n2 = fmaf(e.z, f1.x, n2);
            n3 = fmaf(e.w, f1.y, n3);
        }
    }

    pnum[warp][lane] = make_float4(n0, n1, n2, n3);
    pden[warp][lane] = make_float4(d0, d1, d2, d3);
    __syncthreads();

    if (half == 0) {
        float4 on = pnum[warp + 1][lane];
        float4 od = pden[warp + 1][lane];
        n0 += on.x; n1 += on.y; n2 += on.z; n3 += on.w;
        d0 += od.x; d1 += od.y; d2 += od.z; d3 += od.w;

        #pragma unroll
        for (int msk = 32; msk >= 1; msk >>= 1) {
            d0 += __shfl_xor(d0, msk);
            d1 += __shfl_xor(d1, msk);
            d2 += __shfl_xor(d2, msk);
            d3 += __shfl_xor(d3, msk);
        }

        float r = 0.f;
        if (deg > 0)
            r = 0.25f * (n0 / d0 + n1 / d1 + n2 / d2 + n3 / d3);
        out[(size_t)d * 64 + lane] = r + bias[lane];
    }
}

extern "C" void kernel_launch(void* const* d_in, const int* in_sizes, int n_in,
                              void* d_out, int out_size, void* d_ws, size_t ws_size,
                              hipStream_t stream) {
    const float* x        = (const float*)d_in[0];
    const int*   ei       = (const int*)  d_in[1];
    const int*   etype    = (const int*)  d_in[2];
    const float* rel_emb  = (const float*)d_in[3];
    const float* W        = (const float*)d_in[4];
    const float* W_e      = (const float*)d_in[5];
    const float* att_src  = (const float*)d_in[6];
    const float* att_dst  = (const float*)d_in[7];
    const float* att_edge = (const float*)d_in[8];
    const float* bias     = (const float*)d_in[9];
    float* out = (float*)d_out;

    char* ws = (char*)d_ws;
    __half* xh      = (__half*)ws;                              // 25.6 MB
    char* p = ws + (size_t)N_NODES * 256 * 2;
    int*   counts   = (int*)p;                p += N_NODES * 4;   // zeroed
    float* a_src    = (float*)p;              p += N_NODES * 4 * 4;
    float* a_dst    = (float*)p;              p += N_NODES * 4 * 4;
    float* a_edge_r = (float*)p;              p += NREL * 4 * 4;
    int*   offsets  = (int*)p;                p += N_NODES * 4;
    int*   rank     = (int*)p;                p += (size_t)N_EDGES * 4;
    int*   elist    = (int*)p;                p += (size_t)N_EDGES * 4;

    hipMemsetAsync(counts, 0, N_NODES * sizeof(int), stream);
    mega_kernel<<<NXB + HIST_NB + NREL, 256, 0, stream>>>(
        x, W, att_src, att_dst, xh, a_src, a_dst,
        ei, counts, rank, rel_emb, W_e, att_edge, a_edge_r);
    scan_fused<<<SCAN_NB, 256, 0, stream>>>(counts, offsets);
    scatter_kernel<<<HIST_NB, 256, 0, stream>>>(ei, etype, offsets, rank, elist);
    aggregate<<<N_NODES / 2, 256, 0, stream>>>(offsets, counts, elist, a_src,
                                               a_dst, a_edge_r, xh, bias, out);
}

// Round 17
// 147.460 us; speedup vs baseline: 1.2156x; 1.2156x over previous
//
#include <hip/hip_runtime.h>
#include <hip/hip_fp16.h>

#define N_NODES 50000
#define N_EDGES 800000
#define NREL 32
#define NEG_SLOPE 0.2f
#define SCAN_NB ((N_NODES + 255) / 256)   // 196
#define HIST_NB ((N_EDGES + 255) / 256)   // 3125
#define NXB 256                           // nx blocks in MEGA
#define NTILES (N_NODES / 16)             // 3125 wave tiles (exact)

typedef _Float16 f16x8 __attribute__((ext_vector_type(8)));
typedef float f32x4 __attribute__((ext_vector_type(4)));

// ---------------- MEGA: nx_mfma (blocks 0..255) ∥ hist (256..3380) ∥ rel (3381..3412) ----------------
__global__ __launch_bounds__(256) void mega_kernel(
    const float* __restrict__ x, const float* __restrict__ W,
    const float* __restrict__ att_src, const float* __restrict__ att_dst,
    __half* __restrict__ xh, float* __restrict__ a_src, float* __restrict__ a_dst,
    const int* __restrict__ ei, int* __restrict__ counts, int* __restrict__ rank,
    const float* __restrict__ rel_emb, const float* __restrict__ W_e,
    const float* __restrict__ att_edge, float* __restrict__ a_edge_r)
{
    __shared__ __align__(16) _Float16 Wl[272][72];
    int tid = threadIdx.x;
    int bid = blockIdx.x;

    if (bid >= NXB) {
        if (bid < NXB + HIST_NB) {
            // ---- histogram + rank ----
            int e = (bid - NXB) * 256 + tid;
            if (e < N_EDGES) rank[e] = atomicAdd(&counts[ei[N_EDGES + e]], 1);
        } else if (tid < 64) {
            // ---- relation table row r ----
            int r = bid - (NXB + HIST_NB);
            int h = tid >> 4;
            int i16 = tid & 15;
            float rr = rel_emb[r * 64 + tid];
            float4 acc = {0.f, 0.f, 0.f, 0.f};
            #pragma unroll
            for (int k = 0; k < 64; ++k) {
                float rv = __shfl(rr, k);
                float4 wv = *(const float4*)(W_e + k * 256 + h * 64 + i16 * 4);
                acc.x += rv * wv.x; acc.y += rv * wv.y;
                acc.z += rv * wv.z; acc.w += rv * wv.w;
            }
            float4 aev = *(const float4*)(att_edge + h * 64 + i16 * 4);
            float ae = acc.x * aev.x + acc.y * aev.y + acc.z * aev.z + acc.w * aev.w;
            #pragma unroll
            for (int m = 8; m >= 1; m >>= 1) ae += __shfl_xor(ae, m);
            if (i16 == 0) a_edge_r[r * 4 + h] = ae;
        }
        return;
    }

    // ---- node transform via MFMA ----
    for (int idx = tid; idx < 64 * 256; idx += 256) {
        int k = idx >> 8, col = idx & 255;
        Wl[col][k] = (_Float16)W[idx];
    }
    // vsd computed inline (fp32 accumulate): cols 256..263; zero 264..271
    for (int idx = tid; idx < 512; idx += 256) {
        int k = idx & 63;
        int col8 = idx >> 6;
        int h = col8 >> 1;
        const float* att = (col8 & 1) ? att_dst : att_src;
        float s = 0.f;
        #pragma unroll 8
        for (int c = 0; c < 64; ++c)
            s += W[k * 256 + h * 64 + c] * att[h * 64 + c];
        Wl[256 + col8][k] = (_Float16)s;
        Wl[264 + col8][k] = (_Float16)0.f;
    }
    __syncthreads();

    int lane = tid & 63;
    int wv = tid >> 6;
    int r16 = lane & 15;
    int kg = lane >> 4;

    for (int tile = bid * 4 + wv; tile < NTILES; tile += NXB * 4) {
        int nb = tile * 16;
        const float* __restrict__ xrow = x + (size_t)(nb + r16) * 64 + kg * 8;
        float4 u0 = *(const float4*)(xrow);
        float4 u1 = *(const float4*)(xrow + 4);
        float4 u2 = *(const float4*)(xrow + 32);
        float4 u3 = *(const float4*)(xrow + 36);
        f16x8 A0, A1;
        A0[0] = (_Float16)u0.x; A0[1] = (_Float16)u0.y;
        A0[2] = (_Float16)u0.z; A0[3] = (_Float16)u0.w;
        A0[4] = (_Float16)u1.x; A0[5] = (_Float16)u1.y;
        A0[6] = (_Float16)u1.z; A0[7] = (_Float16)u1.w;
        A1[0] = (_Float16)u2.x; A1[1] = (_Float16)u2.y;
        A1[2] = (_Float16)u2.z; A1[3] = (_Float16)u2.w;
        A1[4] = (_Float16)u3.x; A1[5] = (_Float16)u3.y;
        A1[6] = (_Float16)u3.z; A1[7] = (_Float16)u3.w;

        f32x4 D[17];
        #pragma unroll
        for (int ct = 0; ct < 17; ++ct) {
            f16x8 B0 = *(const f16x8*)&Wl[ct * 16 + r16][kg * 8];
            f16x8 B1 = *(const f16x8*)&Wl[ct * 16 + r16][32 + kg * 8];
            f32x4 d = {0.f, 0.f, 0.f, 0.f};
            d = __builtin_amdgcn_mfma_f32_16x16x32_f16(A0, B0, d, 0, 0, 0);
            d = __builtin_amdgcn_mfma_f32_16x16x32_f16(A1, B1, d, 0, 0, 0);
            D[ct] = d;
        }

        #pragma unroll
        for (int r = 0; r < 4; ++r) {
            int n = nb + kg * 4 + r;
            #pragma unroll
            for (int j = 0; j < 4; ++j) {
                __half2 lo = __floats2half2_rn(D[j][r], D[j + 4][r]);
                __half2 hi = __floats2half2_rn(D[j + 8][r], D[j + 12][r]);
                uint2 pk;
                pk.x = *(unsigned int*)&lo;
                pk.y = *(unsigned int*)&hi;
                *(uint2*)(xh + (size_t)n * 256 + (j * 16 + r16) * 4) = pk;
            }
            if (r16 < 8) {
                float v = D[16][r];
                int h = r16 >> 1;
                if (r16 & 1) a_dst[n * 4 + h] = v;
                else         a_src[n * 4 + h] = v;
            }
        }
    }
}

// ---------------- scan1: block-level exclusive scan ----------------
__global__ __launch_bounds__(256) void scan1_kernel(const int* __restrict__ counts,
                                                    int* __restrict__ offsets,
                                                    int* __restrict__ blocksums) {
    __shared__ int sh[256];
    int tid = threadIdx.x;
    int i = blockIdx.x * 256 + tid;
    int v = (i < N_NODES) ? counts[i] : 0;
    sh[tid] = v;
    __syncthreads();
    #pragma unroll
    for (int off = 1; off < 256; off <<= 1) {
        int t = (tid >= off) ? sh[tid - off] : 0;
        __syncthreads();
        sh[tid] += t;
        __syncthreads();
    }
    if (i < N_NODES) offsets[i] = sh[tid] - v;
    if (tid == 255) blocksums[blockIdx.x] = sh[255];
}

// ---------------- scan23: each block derives its own offset via masked reduce ----------------
__global__ __launch_bounds__(256) void scan23_kernel(int* __restrict__ offsets,
                                                     const int* __restrict__ blocksums) {
    __shared__ int wsum[4];
    int tid = threadIdx.x;
    int lane = tid & 63;
    int warp = tid >> 6;

    int v = (tid < SCAN_NB && tid < (int)blockIdx.x) ? blocksums[tid] : 0;
    #pragma unroll
    for (int m = 32; m >= 1; m >>= 1) v += __shfl_xor(v, m);
    if (lane == 0) wsum[warp] = v;
    __syncthreads();
    int boff = wsum[0] + wsum[1] + wsum[2] + wsum[3];

    int i = blockIdx.x * 256 + tid;
    if (i < N_NODES) offsets[i] += boff;
}

// ---------------- scatter: pos = offsets[d] + rank[e]  (no atomic) ----------------
__global__ __launch_bounds__(256) void scatter_kernel(const int* __restrict__ ei,
                                                      const int* __restrict__ etype,
                                                      const int* __restrict__ offsets,
                                                      const int* __restrict__ rank,
                                                      int* __restrict__ elist) {
    int e = blockIdx.x * 256 + threadIdx.x;
    if (e >= N_EDGES) return;
    int s = ei[e];
    int d = ei[N_EDGES + e];
    int t = etype[e];
    int pos = offsets[d] + rank[e];
    elist[pos] = (s << 5) | t;
}

// ---------------- aggregate (2 waves per dst node, inline exp) ----------------
__global__ __launch_bounds__(256) void aggregate(
    const int* __restrict__ offsets, const int* __restrict__ counts,
    const int* __restrict__ elist, const float* __restrict__ a_src,
    const float* __restrict__ a_dst, const float* __restrict__ a_edge_r,
    const __half* __restrict__ xh, const float* __restrict__ bias,
    float* __restrict__ out)
{
    __shared__ float4 exsh[4][64];
    __shared__ int    ssh[4][64];
    __shared__ float4 pnum[4][64];
    __shared__ float4 pden[4][64];

    int lane = threadIdx.x & 63;
    int warp = threadIdx.x >> 6;   // 0..3
    int pair = warp >> 1;
    int half = warp & 1;
    int d = blockIdx.x * 2 + pair;

    int beg = offsets[d];
    int deg = counts[d];
    int h1 = (deg + 1) >> 1;
    int mybeg = beg + (half ? h1 : 0);
    int mydeg = half ? (deg - h1) : h1;

    float4 advec = ((const float4*)a_dst)[d];

    float n0 = 0.f, n1 = 0.f, n2 = 0.f, n3 = 0.f;
    float d0 = 0.f, d1 = 0.f, d2 = 0.f, d3 = 0.f;

    for (int base = 0; base < mydeg; base += 64) {
        int m = mydeg - base; if (m > 64) m = 64;

        float4 ev = make_float4(0.f, 0.f, 0.f, 0.f);
        int s = 0;
        if (lane < m) {
            int pk = elist[mybeg + base + lane];
            s = pk >> 5;
            int t = pk & 31;
            float4 as = ((const float4*)a_src)[s];
            float4 ae = ((const float4*)a_edge_r)[t];
            float b0 = as.x + advec.x + ae.x; b0 = b0 > 0.f ? b0 : NEG_SLOPE * b0;
            float b1 = as.y + advec.y + ae.y; b1 = b1 > 0.f ? b1 : NEG_SLOPE * b1;
            float b2 = as.z + advec.z + ae.z; b2 = b2 > 0.f ? b2 : NEG_SLOPE * b2;
            float b3 = as.w + advec.w + ae.w; b3 = b3 > 0.f ? b3 : NEG_SLOPE * b3;
            ev.x = __expf(b0); ev.y = __expf(b1);
            ev.z = __expf(b2); ev.w = __expf(b3);
        }
        d0 += ev.x; d1 += ev.y; d2 += ev.z; d3 += ev.w;
        exsh[warp][lane] = ev;   // wave-private rows; wave-synchronous RAW
        ssh[warp][lane]  = s;

        #pragma unroll 4
        for (int j = 0; j < m; ++j) {
            float4 e = exsh[warp][j];   // broadcast read (no conflict)
            int sj = ssh[warp][j];
            const __half2* __restrict__ xr =
                (const __half2*)(xh + (size_t)sj * 256 + lane * 4);
            __half2 p0 = xr[0], p1 = xr[1];
            float2 f0 = __half22float2(p0), f1 = __half22float2(p1);
            n0 = fmaf(e.x, f0.x, n0);
            n1 = fmaf(e.y, f0.y, n1);
            n2 = fmaf(e.z, f1.x, n2);
            n3 = fmaf(e.w, f1.y, n3);
        }
    }

    pnum[warp][lane] = make_float4(n0, n1, n2, n3);
    pden[warp][lane] = make_float4(d0, d1, d2, d3);
    __syncthreads();

    if (half == 0) {
        float4 on = pnum[warp + 1][lane];
        float4 od = pden[warp + 1][lane];
        n0 += on.x; n1 += on.y; n2 += on.z; n3 += on.w;
        d0 += od.x; d1 += od.y; d2 += od.z; d3 += od.w;

        #pragma unroll
        for (int msk = 32; msk >= 1; msk >>= 1) {
            d0 += __shfl_xor(d0, msk);
            d1 += __shfl_xor(d1, msk);
            d2 += __shfl_xor(d2, msk);
            d3 += __shfl_xor(d3, msk);
        }

        float r = 0.f;
        if (deg > 0)
            r = 0.25f * (n0 / d0 + n1 / d1 + n2 / d2 + n3 / d3);
        out[(size_t)d * 64 + lane] = r + bias[lane];
    }
}

extern "C" void kernel_launch(void* const* d_in, const int* in_sizes, int n_in,
                              void* d_out, int out_size, void* d_ws, size_t ws_size,
                              hipStream_t stream) {
    const float* x        = (const float*)d_in[0];
    const int*   ei       = (const int*)  d_in[1];
    const int*   etype    = (const int*)  d_in[2];
    const float* rel_emb  = (const float*)d_in[3];
    const float* W        = (const float*)d_in[4];
    const float* W_e      = (const float*)d_in[5];
    const float* att_src  = (const float*)d_in[6];
    const float* att_dst  = (const float*)d_in[7];
    const float* att_edge = (const float*)d_in[8];
    const float* bias     = (const float*)d_in[9];
    float* out = (float*)d_out;

    char* ws = (char*)d_ws;
    __half* xh      = (__half*)ws;                              // 25.6 MB
    char* p = ws + (size_t)N_NODES * 256 * 2;
    int*   counts   = (int*)p;                p += N_NODES * 4;   // zeroed
    float* a_src    = (float*)p;              p += N_NODES * 4 * 4;
    float* a_dst    = (float*)p;              p += N_NODES * 4 * 4;
    float* a_edge_r = (float*)p;              p += NREL * 4 * 4;
    int*   offsets  = (int*)p;                p += N_NODES * 4;
    int*   blocksums= (int*)p;                p += 256 * 4;
    int*   rank     = (int*)p;                p += (size_t)N_EDGES * 4;
    int*   elist    = (int*)p;                p += (size_t)N_EDGES * 4;

    hipMemsetAsync(counts, 0, N_NODES * sizeof(int), stream);
    mega_kernel<<<NXB + HIST_NB + NREL, 256, 0, stream>>>(
        x, W, att_src, att_dst, xh, a_src, a_dst,
        ei, counts, rank, rel_emb, W_e, att_edge, a_edge_r);
    scan1_kernel<<<SCAN_NB, 256, 0, stream>>>(counts, offsets, blocksums);
    scan23_kernel<<<SCAN_NB, 256, 0, stream>>>(offsets, blocksums);
    scatter_kernel<<<HIST_NB, 256, 0, stream>>>(ei, etype, offsets, rank, elist);
    aggregate<<<N_NODES / 2, 256, 0, stream>>>(offsets, counts, elist, a_src,
                                               a_dst, a_edge_r, xh, bias, out);
}